// Round 12
// baseline (283.002 us; speedup 1.0000x reference)
//
#include <hip/hip_runtime.h>
#include <math.h>

// GCN 2-layer forward, zero global atomics, native LDS fp atomics.
// Round-9 A/B: agg kernels invariant to TLP (12->62% occ) and ILP (int4x4) at
// ~75us, VALU 1%, HBM 4%. Theory: shared-mem f32 atomicAdd compiles to a
// ds_cmpst CAS RETRY LOOP (fp atomics gated behind unsafe-fp-atomics, same as
// the Round-4 global-atomic pathology). Fix: unsafeAtomicAdd on the LDS
// accumulators -> native ds_add_f32. Everything else identical to Round 9.
//
//   out = log_softmax( Dinv(A+I)Dinv' relu( Dinv(A+I)Dinv' X W1 + b1 ) W2 + b2 )
// Aggregation commutes with W1 -> both layers aggregate 4-vectors.

#define BLK   256
#define G     512      // binning chunks
#define SH    8        // log2(nodes per bucket)
#define S     256      // nodes per bucket
#define MAXNB 512      // LDS bucket-table capacity (NB = 391)

// ---- pass A: per-chunk bucket histogram (LDS int atomics, int4-batched) ----
__global__ void __launch_bounds__(BLK) k_binA(const int* __restrict__ dst,
                                              int* __restrict__ gh,
                                              int E, int NB, int chunk) {
    __shared__ int hist[MAXNB];
    int g = blockIdx.x, t = threadIdx.x;
    for (int j = t; j < NB; j += BLK) hist[j] = 0;
    __syncthreads();
    int bs = g * chunk, be = min(bs + chunk, E);
    int bs4 = (bs + 3) & ~3, be4 = be & ~3;
    if (be4 <= bs4) {
        for (int e = bs + t; e < be; e += BLK)
            atomicAdd(&hist[dst[e] >> SH], 1);
    } else {
        if (t < bs4 - bs) atomicAdd(&hist[dst[bs + t] >> SH], 1);
        for (int e = bs4 + 4 * t; e < be4; e += 4 * BLK) {
            int4 d = *reinterpret_cast<const int4*>(dst + e);
            atomicAdd(&hist[d.x >> SH], 1);
            atomicAdd(&hist[d.y >> SH], 1);
            atomicAdd(&hist[d.z >> SH], 1);
            atomicAdd(&hist[d.w >> SH], 1);
        }
        if (t < be - be4) atomicAdd(&hist[dst[be4 + t] >> SH], 1);
    }
    __syncthreads();
    for (int j = t; j < NB; j += BLK) gh[j * G + g] = hist[j];  // [bucket][chunk]
}

// ---- 3-kernel exclusive scan over m = NB*G elements (in place) ----
__global__ void __launch_bounds__(BLK) k_scanA(const int* __restrict__ a,
                                               int* __restrict__ bsum, int m) {
    __shared__ int sh[BLK];
    int i = blockIdx.x * BLK + threadIdx.x;
    sh[threadIdx.x] = (i < m) ? a[i] : 0;
    __syncthreads();
    for (int off = BLK >> 1; off > 0; off >>= 1) {
        if (threadIdx.x < off) sh[threadIdx.x] += sh[threadIdx.x + off];
        __syncthreads();
    }
    if (threadIdx.x == 0) bsum[blockIdx.x] = sh[0];
}

__global__ void __launch_bounds__(1024) k_scanB(const int* __restrict__ bsum,
                                                int* __restrict__ boff, int nb) {
    __shared__ int sh[1024];
    int t = threadIdx.x;
    int v = (t < nb) ? bsum[t] : 0;
    sh[t] = v; __syncthreads();
    for (int off = 1; off < 1024; off <<= 1) {
        int u = (t >= off) ? sh[t - off] : 0;
        __syncthreads();
        sh[t] += u;
        __syncthreads();
    }
    if (t < nb) boff[t] = sh[t] - v;   // exclusive
}

__global__ void __launch_bounds__(BLK) k_scanC(int* __restrict__ a,
                                               const int* __restrict__ boff, int m) {
    __shared__ int sh[BLK];
    int t = threadIdx.x;
    int i = blockIdx.x * BLK + t;
    int v = (i < m) ? a[i] : 0;
    sh[t] = v; __syncthreads();
    for (int off = 1; off < BLK; off <<= 1) {
        int u = (t >= off) ? sh[t - off] : 0;
        __syncthreads();
        sh[t] += u;
        __syncthreads();
    }
    if (i < m) a[i] = sh[t] - v + boff[blockIdx.x];
}

// ---- pass B: scatter packed edges into bucket-contiguous runs ----
// word = src | (dst&255)<<24   (src < 2^24)
__global__ void __launch_bounds__(BLK) k_binB(const int* __restrict__ src,
                                              const int* __restrict__ dst,
                                              const int* __restrict__ offs,
                                              int* __restrict__ words,
                                              int E, int NB, int chunk) {
    __shared__ int cur[MAXNB];
    int g = blockIdx.x, t = threadIdx.x;
    for (int j = t; j < NB; j += BLK) cur[j] = offs[j * G + g];
    __syncthreads();
    int bs = g * chunk, be = min(bs + chunk, E);
    int bs4 = (bs + 3) & ~3, be4 = be & ~3;
    if (be4 <= bs4) {
        for (int e = bs + t; e < be; e += BLK) {
            int d = dst[e];
            int pos = atomicAdd(&cur[d >> SH], 1);
            words[pos] = src[e] | ((d & (S - 1)) << 24);
        }
    } else {
        if (t < bs4 - bs) {
            int e = bs + t, d = dst[e];
            int pos = atomicAdd(&cur[d >> SH], 1);
            words[pos] = src[e] | ((d & (S - 1)) << 24);
        }
        for (int e = bs4 + 4 * t; e < be4; e += 4 * BLK) {
            int4 d = *reinterpret_cast<const int4*>(dst + e);
            int4 s = *reinterpret_cast<const int4*>(src + e);
            int p0 = atomicAdd(&cur[d.x >> SH], 1);
            int p1 = atomicAdd(&cur[d.y >> SH], 1);
            int p2 = atomicAdd(&cur[d.z >> SH], 1);
            int p3 = atomicAdd(&cur[d.w >> SH], 1);
            words[p0] = s.x | ((d.x & (S - 1)) << 24);
            words[p1] = s.y | ((d.y & (S - 1)) << 24);
            words[p2] = s.z | ((d.z & (S - 1)) << 24);
            words[p3] = s.w | ((d.w & (S - 1)) << 24);
        }
        if (t < be - be4) {
            int e = be4 + t, d = dst[e];
            int pos = atomicAdd(&cur[d >> SH], 1);
            words[pos] = src[e] | ((d & (S - 1)) << 24);
        }
    }
}

// ---- degree: K-way split per bucket, LDS count (int4-batched) ----
__global__ void __launch_bounds__(BLK) k_cnt_split(const int* __restrict__ words,
                                                   const int* __restrict__ offs,
                                                   int* __restrict__ pcnt,
                                                   int E, int NB, int K) {
    __shared__ int cnt[S];
    int b = blockIdx.x / K, k = blockIdx.x % K, t = threadIdx.x;
    cnt[t] = 0;
    __syncthreads();
    int e0 = offs[b * G];
    int e1 = (b + 1 < NB) ? offs[(b + 1) * G] : E;
    long len = e1 - e0;
    int bs = e0 + (int)(len * k / K);
    int be = e0 + (int)(len * (k + 1) / K);
    int bs4 = (bs + 3) & ~3, be4 = be & ~3;
    if (be4 <= bs4) {
        for (int e = bs + t; e < be; e += BLK)
            atomicAdd(&cnt[((unsigned)words[e]) >> 24], 1);
    } else {
        if (t < bs4 - bs) atomicAdd(&cnt[((unsigned)words[bs + t]) >> 24], 1);
        for (int e = bs4 + 4 * t; e < be4; e += 4 * BLK) {
            int4 w = *reinterpret_cast<const int4*>(words + e);
            atomicAdd(&cnt[((unsigned)w.x) >> 24], 1);
            atomicAdd(&cnt[((unsigned)w.y) >> 24], 1);
            atomicAdd(&cnt[((unsigned)w.z) >> 24], 1);
            atomicAdd(&cnt[((unsigned)w.w) >> 24], 1);
        }
        if (t < be - be4) atomicAdd(&cnt[((unsigned)words[be4 + t]) >> 24], 1);
    }
    __syncthreads();
    pcnt[(b * K + k) * S + t] = cnt[t];            // coalesced
}

// ---- combine degree partials; dinv = rsqrt(deg+1); xd = x*dinv ----
__global__ void __launch_bounds__(BLK) k_cnt_comb(const int* __restrict__ pcnt,
                                                  const float* __restrict__ x,
                                                  float* __restrict__ dinv,
                                                  float* __restrict__ xd,
                                                  int n, int K) {
    int b = blockIdx.x, t = threadIdx.x;
    int node = b * S + t;
    if (node >= n) return;
    int c = 0;
    for (int k = 0; k < K; ++k) c += pcnt[(b * K + k) * S + t];
    float di = rsqrtf((float)(c + 1));             // +1 self-loop
    dinv[node] = di;
    float4 xv = reinterpret_cast<const float4*>(x)[node];
    float4 o = { xv.x * di, xv.y * di, xv.z * di, xv.w * di };
    reinterpret_cast<float4*>(xd)[node] = o;
}

// ---- aggregation split: int4 word batch + gathers + NATIVE LDS f32 atomics ----
__device__ __forceinline__ void agg_one(float* agg, unsigned w, const float4* feat4) {
    int s  = w & 0xFFFFFF;
    int dl = w >> 24;
    float4 v = feat4[s];
    unsafeAtomicAdd(&agg[dl],         v.x);
    unsafeAtomicAdd(&agg[S + dl],     v.y);
    unsafeAtomicAdd(&agg[2 * S + dl], v.z);
    unsafeAtomicAdd(&agg[3 * S + dl], v.w);
}

__global__ void __launch_bounds__(BLK) k_agg_split(const int* __restrict__ words,
                                                   const int* __restrict__ offs,
                                                   const float* __restrict__ feat,
                                                   float4* __restrict__ pagg,
                                                   int E, int NB, int K) {
    __shared__ float agg[4 * S];
    int b = blockIdx.x / K, k = blockIdx.x % K, t = threadIdx.x;
    agg[t] = 0.f; agg[S + t] = 0.f; agg[2 * S + t] = 0.f; agg[3 * S + t] = 0.f;
    __syncthreads();
    const float4* feat4 = reinterpret_cast<const float4*>(feat);
    int e0 = offs[b * G];
    int e1 = (b + 1 < NB) ? offs[(b + 1) * G] : E;
    long len = e1 - e0;
    int bs = e0 + (int)(len * k / K);
    int be = e0 + (int)(len * (k + 1) / K);
    int bs4 = (bs + 3) & ~3, be4 = be & ~3;
    if (be4 <= bs4) {
        for (int e = bs + t; e < be; e += BLK)
            agg_one(agg, (unsigned)words[e], feat4);
    } else {
        if (t < bs4 - bs) agg_one(agg, (unsigned)words[bs + t], feat4);
        for (int e = bs4 + 4 * t; e < be4; e += 4 * BLK) {
            int4 wv = *reinterpret_cast<const int4*>(words + e);
            unsigned w0 = wv.x, w1 = wv.y, w2 = wv.z, w3 = wv.w;
            // 4 independent gathers issue back-to-back
            float4 v0 = feat4[w0 & 0xFFFFFF];
            float4 v1 = feat4[w1 & 0xFFFFFF];
            float4 v2 = feat4[w2 & 0xFFFFFF];
            float4 v3 = feat4[w3 & 0xFFFFFF];
            int d0 = w0 >> 24, d1 = w1 >> 24, d2 = w2 >> 24, d3 = w3 >> 24;
            unsafeAtomicAdd(&agg[d0], v0.x);         unsafeAtomicAdd(&agg[S + d0], v0.y);
            unsafeAtomicAdd(&agg[2 * S + d0], v0.z); unsafeAtomicAdd(&agg[3 * S + d0], v0.w);
            unsafeAtomicAdd(&agg[d1], v1.x);         unsafeAtomicAdd(&agg[S + d1], v1.y);
            unsafeAtomicAdd(&agg[2 * S + d1], v1.z); unsafeAtomicAdd(&agg[3 * S + d1], v1.w);
            unsafeAtomicAdd(&agg[d2], v2.x);         unsafeAtomicAdd(&agg[S + d2], v2.y);
            unsafeAtomicAdd(&agg[2 * S + d2], v2.z); unsafeAtomicAdd(&agg[3 * S + d2], v2.w);
            unsafeAtomicAdd(&agg[d3], v3.x);         unsafeAtomicAdd(&agg[S + d3], v3.y);
            unsafeAtomicAdd(&agg[2 * S + d3], v3.z); unsafeAtomicAdd(&agg[3 * S + d3], v3.w);
        }
        if (t < be - be4) agg_one(agg, (unsigned)words[be4 + t], feat4);
    }
    __syncthreads();
    float4 p = { agg[t], agg[S + t], agg[2 * S + t], agg[3 * S + t] };
    pagg[(b * K + k) * S + t] = p;                 // coalesced
}

// ---- layer-1 combine: sum partials + self + fused 4->16(relu)->4 MLP ----
__global__ void __launch_bounds__(BLK) k_comb1(const float4* __restrict__ pagg,
                                               const float* __restrict__ dinv,
                                               const float* __restrict__ xd,
                                               const float* __restrict__ W1,
                                               const float* __restrict__ b1,
                                               const float* __restrict__ W2,
                                               float* __restrict__ g2,
                                               int n, int K) {
    int b = blockIdx.x, t = threadIdx.x;
    int node = b * S + t;
    if (node >= n) return;
    float4 s = reinterpret_cast<const float4*>(xd)[node];   // self-loop term
    for (int k = 0; k < K; ++k) {
        float4 p = pagg[(b * K + k) * S + t];
        s.x += p.x; s.y += p.y; s.z += p.z; s.w += p.w;
    }
    float di = dinv[node];
    float o0 = 0.f, o1 = 0.f, o2 = 0.f, o3 = 0.f;
#pragma unroll
    for (int j = 0; j < 16; ++j) {
        // W1 [4][16] row-major; wave-uniform -> scalar broadcast
        float h = s.x * W1[j] + s.y * W1[16 + j] + s.z * W1[32 + j] + s.w * W1[48 + j];
        float v = di * h + b1[j];
        v = v > 0.f ? v : 0.f;   // relu
        o0 += v * W2[j * 4 + 0];
        o1 += v * W2[j * 4 + 1];
        o2 += v * W2[j * 4 + 2];
        o3 += v * W2[j * 4 + 3];
    }
    float4 o = { o0 * di, o1 * di, o2 * di, o3 * di };
    reinterpret_cast<float4*>(g2)[node] = o;
}

// ---- layer-2 combine: sum partials + self + bias + log_softmax ----
__global__ void __launch_bounds__(BLK) k_comb2(const float4* __restrict__ pagg,
                                               const float* __restrict__ dinv,
                                               const float* __restrict__ g2,
                                               const float* __restrict__ b2,
                                               float* __restrict__ out,
                                               int n, int K) {
    int b = blockIdx.x, t = threadIdx.x;
    int node = b * S + t;
    if (node >= n) return;
    float4 s = reinterpret_cast<const float4*>(g2)[node];   // self-loop term
    for (int k = 0; k < K; ++k) {
        float4 p = pagg[(b * K + k) * S + t];
        s.x += p.x; s.y += p.y; s.z += p.z; s.w += p.w;
    }
    float di = dinv[node];
    float o0 = di * s.x + b2[0];
    float o1 = di * s.y + b2[1];
    float o2 = di * s.z + b2[2];
    float o3 = di * s.w + b2[3];
    float m = fmaxf(fmaxf(o0, o1), fmaxf(o2, o3));
    float sm = expf(o0 - m) + expf(o1 - m) + expf(o2 - m) + expf(o3 - m);
    float l = m + logf(sm);
    float4 r = { o0 - l, o1 - l, o2 - l, o3 - l };
    reinterpret_cast<float4*>(out)[node] = r;
}

extern "C" void kernel_launch(void* const* d_in, const int* in_sizes, int n_in,
                              void* d_out, int out_size, void* d_ws, size_t ws_size,
                              hipStream_t stream) {
    const float* x  = (const float*)d_in[0];
    const float* W1 = (const float*)d_in[1];
    const float* b1 = (const float*)d_in[2];
    const float* W2 = (const float*)d_in[3];
    const float* b2 = (const float*)d_in[4];
    const int*   ei = (const int*)d_in[5];

    const int n = in_sizes[0] / 4;   // 100000
    const int E = in_sizes[5] / 2;   // 3200000
    const int* src = ei;
    const int* dst = ei + E;

    const int NB    = (n + S - 1) / S;        // 391 buckets
    const int chunk = (E + G - 1) / G;        // 6250 edges/chunk
    const int m     = NB * G;                 // 200192 scan elements
    const int mB    = (m + BLK - 1) / BLK;    // 782 (<= 1024 for scanB)

    // workspace layout (16B-aligned)
    char* ws = (char*)d_ws;
    size_t off = 0;
    int*    words = (int*)   (ws + off); off += (size_t)E * 4;    // 12.8 MB
    int*    offs  = (int*)   (ws + off); off += (size_t)m * 4;    // 800 KB
    float*  xd    = (float*) (ws + off); off += (size_t)n * 16;   // 1.6 MB
    float*  g2    = (float*) (ws + off); off += (size_t)n * 16;   // 1.6 MB
    float*  dinv  = (float*) (ws + off); off += (size_t)n * 4;    // 400 KB
    int*    bsum  = (int*)   (ws + off); off += 4096;
    int*    boff  = (int*)   (ws + off); off += 4096;
    // partial buffer: f32x4 partials for agg; int partials for degree alias it
    float4* pagg  = (float4*)(ws + off);
    int*    pcnt  = (int*)   (ws + off);
    size_t base = off;
    int K = 8;
    while (K > 1 && base + (size_t)NB * K * S * 16 > ws_size) K >>= 1;
    float* out = (float*)d_out;

    k_binA     <<<G,      BLK,  0, stream>>>(dst, offs, E, NB, chunk);
    k_scanA    <<<mB,     BLK,  0, stream>>>(offs, bsum, m);
    k_scanB    <<<1,      1024, 0, stream>>>(bsum, boff, mB);
    k_scanC    <<<mB,     BLK,  0, stream>>>(offs, boff, m);
    k_binB     <<<G,      BLK,  0, stream>>>(src, dst, offs, words, E, NB, chunk);
    k_cnt_split<<<NB * K, BLK,  0, stream>>>(words, offs, pcnt, E, NB, K);
    k_cnt_comb <<<NB,     BLK,  0, stream>>>(pcnt, x, dinv, xd, n, K);
    k_agg_split<<<NB * K, BLK,  0, stream>>>(words, offs, xd, pagg, E, NB, K);
    k_comb1    <<<NB,     BLK,  0, stream>>>(pagg, dinv, xd, W1, b1, W2, g2, n, K);
    k_agg_split<<<NB * K, BLK,  0, stream>>>(words, offs, g2, pagg, E, NB, K);
    k_comb2    <<<NB,     BLK,  0, stream>>>(pagg, dinv, g2, b2, out, n, K);
}